// Round 1
// baseline (1312.166 us; speedup 1.0000x reference)
//
#include <hip/hip_runtime.h>
#include <math.h>

#define B_ 4
#define N_ 2048
#define M_ 1024
#define K_ 32
#define HEADS_ 4
#define NH_ 128
#define PI_F 3.14159265358979323846f

// workspace offsets (in floats)
#define OFF_WGW   0            // 128*128
#define OFF_W2    16384        // 130*256  [WB | WG]
#define OFF_CB    49664        // 128
#define OFF_CGV   49792        // 128
#define OFF_WVOT  49920        // 12*128
#define OFF_OUTC  51456        // 4
#define OFF_KW    51460        // B*M*4*132
#define OFF_KB    2214148      // B*M*4
#define OFF_VF    2230532      // B*M*128
#define OFF_BASE  2754820      // B*M*128
// total = 3279108 floats (~13.1 MB)

// ---------- precompute kernels ----------

// WGW[i][j] = sum_r w3v[i][128+r] * wv1[r][j]
__global__ void enf_wgw(const float* __restrict__ w3v, const float* __restrict__ wv1,
                        float* __restrict__ WGW) {
  int o = blockIdx.x * 256 + threadIdx.x;   // 16384
  int i = o >> 7, j = o & 127;
  float acc = 0.f;
  for (int r = 0; r < 128; ++r) acc = fmaf(w3v[i*256 + 128 + r], wv1[r*128 + j], acc);
  WGW[o] = acc;
}

// W2[a][j]: j<128 -> w2v@w3v_b ; j>=128 -> w2v@WGW
__global__ void enf_w2(const float* __restrict__ w2v, const float* __restrict__ w3v,
                       const float* __restrict__ WGW, float* __restrict__ W2) {
  int a = blockIdx.x;       // 0..129
  int j = threadIdx.x;      // 0..255
  float acc = 0.f;
  if (j < 128) {
    for (int i = 0; i < 128; ++i) acc = fmaf(w2v[a*128 + i], w3v[i*256 + j], acc);
  } else {
    int j2 = j - 128;
    for (int i = 0; i < 128; ++i) acc = fmaf(w2v[a*128 + i], WGW[i*128 + j2], acc);
  }
  W2[a*256 + j] = acc;
}

__global__ void enf_consts(const float* __restrict__ b2v, const float* __restrict__ w3v,
                           const float* __restrict__ b3v, const float* __restrict__ WGW,
                           const float* __restrict__ wv1, const float* __restrict__ bv1,
                           const float* __restrict__ wv2, const float* __restrict__ wout,
                           const float* __restrict__ bv2, const float* __restrict__ bout,
                           float* __restrict__ cb, float* __restrict__ cgv,
                           float* __restrict__ wvoT, float* __restrict__ outconst) {
  int t = threadIdx.x;
  if (t < 128) {
    float a1 = 0.f;
    for (int i = 0; i < 128; ++i) a1 = fmaf(b2v[i], w3v[i*256 + t], a1);
    cb[t] = a1 + b3v[t];
    float a2 = 0.f;
    for (int i = 0; i < 128; ++i) a2 = fmaf(b2v[i], WGW[i*128 + t], a2);
    for (int r = 0; r < 128; ++r) a2 = fmaf(b3v[128 + r], wv1[r*128 + t], a2);
    cgv[t] = a2 + bv1[t];
  }
  for (int o = t; o < 1536; o += 256) {
    int r12 = o >> 7, i = o & 127;
    int h = r12 / 3, c = r12 - h*3;
    float acc = 0.f;
    for (int k = 0; k < 128; ++k)
      acc = fmaf(wv2[i*512 + h*128 + k], wout[(h*128 + k)*3 + c], acc);
    wvoT[r12*128 + i] = acc;
  }
  if (t < 3) {
    float acc = bout[t];
    for (int r = 0; r < 512; ++r) acc = fmaf(bv2[r], wout[r*3 + t], acc);
    outconst[t] = acc;
  }
}

// per-(b,m): vf, base, kw, kb
__global__ __launch_bounds__(256) void enf_latent(
    const float* __restrict__ c, const float* __restrict__ wk, const float* __restrict__ bk,
    const float* __restrict__ wvw, const float* __restrict__ bv,
    const float* __restrict__ w3q, const float* __restrict__ b3q,
    const float* __restrict__ w2q, const float* __restrict__ b2q,
    const float* __restrict__ wv1, const float* __restrict__ cb,
    float* __restrict__ kw, float* __restrict__ kb,
    float* __restrict__ vf_o, float* __restrict__ base_o) {
  const int bm = blockIdx.x;
  const int tid = threadIdx.x;
  __shared__ float cl[128];
  __shared__ float kfl[256];
  __shared__ float vfl[128];
  __shared__ float kql[4*128];
  if (tid < 128) cl[tid] = c[(size_t)bm*128 + tid];
  __syncthreads();
  { // kf (kept in LDS only)
    int j = tid;
    float acc = bk[j];
    for (int l = 0; l < 128; ++l) acc = fmaf(cl[l], wk[l*256 + j], acc);
    kfl[j] = acc;
  }
  if (tid < 128) { // vf
    int j = tid;
    float acc = bv[j];
    for (int l = 0; l < 128; ++l) acc = fmaf(cl[l], wvw[l*128 + j], acc);
    vfl[j] = acc;
    vf_o[(size_t)bm*128 + j] = acc;
  }
  __syncthreads();
  // kq[h][j] = sum_a w3q[j][h*64+a] * kf[h*64+a]
  for (int t = tid; t < 512; t += 256) {
    int h = t >> 7, j = t & 127;
    const float* wr = w3q + j*256 + h*64;
    const float* kfh = kfl + h*64;
    float acc = 0.f;
    for (int a = 0; a < 64; ++a) acc = fmaf(wr[a], kfh[a], acc);
    kql[h*128 + j] = acc;
  }
  if (tid < 128) { // base = (vf*(1+cb)) @ wv1
    int j = tid;
    float acc = 0.f;
    for (int i = 0; i < 128; ++i) acc = fmaf(vfl[i]*(1.f + cb[i]), wv1[i*128 + j], acc);
    base_o[(size_t)bm*128 + j] = acc;
  }
  __syncthreads();
  // kw[a][h] = sum_j w2q[a][j]*kq[h][j]   (row stride 132 for alignment)
  for (int t = tid; t < 520; t += 256) {
    int a = t >> 2, h = t & 3;
    const float* w2r = w2q + a*128;
    const float* kqh = kql + h*128;
    float acc = 0.f;
    for (int j = 0; j < 128; ++j) acc = fmaf(w2r[j], kqh[j], acc);
    kw[((size_t)bm*4 + h)*132 + a] = acc;
  }
  if (tid < 4) {
    int h = tid;
    float acc = 0.f;
    for (int j = 0; j < 128; ++j) acc = fmaf(b2q[j], kql[h*128 + j], acc);
    for (int a = 0; a < 64; ++a) acc = fmaf(b3q[h*64 + a], kfl[h*64 + a], acc);
    kb[(size_t)bm*4 + h] = acc;
  }
}

// ---------- main kernel: one block per (b,n) ----------
__global__ __launch_bounds__(256) void enf_main(
    const float* __restrict__ x, const float* __restrict__ p,
    const float* __restrict__ g,
    const float* __restrict__ w1q, const float* __restrict__ w1v,
    const float* __restrict__ W2, const float* __restrict__ wv1,
    const float* __restrict__ cgv, const float* __restrict__ wvoT,
    const float* __restrict__ outconst,
    const float* __restrict__ kw, const float* __restrict__ kb,
    const float* __restrict__ vf, const float* __restrict__ base,
    float* __restrict__ out) {
  const int bn = blockIdx.x;
  const int b = bn >> 11;          // N = 2048
  const int tid = threadIdx.x;
  const int lane = tid & 63;
  const int wid = tid >> 6;

  __shared__ alignas(16) float sfvT_s[130*32];   // later reused as evecT[128][32]
  __shared__ alignas(16) float buf[32*256];      // cand / sfq / W2 tile / tpart+wtile / gt
  __shared__ int   selm[K_];
  __shared__ float seld[K_];
  __shared__ float gkv[K_];
  __shared__ float bi2[K_][2];
  __shared__ float logits_s[K_*HEADS_];
  __shared__ alignas(16) float poL[K_*12];
  __shared__ float wts[K_*HEADS_];
  __shared__ float swt[HEADS_];

  float* cand_df = buf;                  // 128 floats (phase A only; buf free then)
  int*   cand_mi = (int*)(buf + 128);    // 128 ints

  const float x0 = x[bn*2 + 0];
  const float x1 = x[bn*2 + 1];
  const float* pb = p + (size_t)b*M_*2;

  // ---- Phase A: per-wave top-32 extraction (exact (d, m) order) ----
  float dl[4]; int ml[4];
#pragma unroll
  for (int s = 0; s < 4; ++s) {
    int m = wid*256 + s*64 + lane;
    float d0 = x0 - pb[2*m], d1 = x1 - pb[2*m + 1];
    dl[s] = d0*d0 + d1*d1; ml[s] = m;
  }
  for (int it = 0; it < K_; ++it) {
    float md = fminf(fminf(dl[0], dl[1]), fminf(dl[2], dl[3]));
#pragma unroll
    for (int off = 1; off < 64; off <<= 1) md = fminf(md, __shfl_xor(md, off));
    int mi = 0x7fffffff;
#pragma unroll
    for (int s = 0; s < 4; ++s) if (dl[s] == md) mi = min(mi, ml[s]);
#pragma unroll
    for (int off = 1; off < 64; off <<= 1) mi = min(mi, __shfl_xor(mi, off));
    if (lane == 0) { cand_df[wid*K_ + it] = md; cand_mi[wid*K_ + it] = mi; }
#pragma unroll
    for (int s = 0; s < 4; ++s) if (ml[s] == mi) dl[s] = 3.4e38f;
  }
  __syncthreads();
  // merge 128 candidates -> global top-32 via exact rank
  if (tid < 128) {
    float d = cand_df[tid]; int m = cand_mi[tid];
    int rank = 0;
    for (int i = 0; i < 128; ++i) {
      float di = cand_df[i];
      rank += (di < d || (di == d && cand_mi[i] < m)) ? 1 : 0;
    }
    if (rank < K_) { selm[rank] = m; seld[rank] = d; }
  }
  __syncthreads();
  if (tid < K_) gkv[tid] = g[(size_t)b*M_ + selm[tid]];
  if (tid < 2*K_) {
    int e = tid >> 1, cc = tid & 1;
    bi2[e][cc] = (cc ? x1 : x0) - pb[2*selm[e] + cc];
  }
  __syncthreads();

  // ---- Phase B: sin features (sfq row-major in buf, sfv transposed) ----
  float* sfq_s = buf;  // [32][132]
  for (int t = tid; t < 32*130; t += 256) {
    int e = t & 31, col = t >> 5;
    float b0 = bi2[e][0], b1 = bi2[e][1];
    float vq, vv;
    if (col < 2) {
      float bc = col ? b1 : b0;
      vq = __sinf(bc); vv = vq;
    } else if (col < 66) {
      int j = col - 2;
      float s0 = PI_F*(b0 + 1.f), s1 = PI_F*(b1 + 1.f);
      float eq = s0*w1q[j] + s1*w1q[64 + j];
      float ev = s0*w1v[j] + s1*w1v[64 + j];
      vq = __sinf(eq); vv = __sinf(ev);
    } else {
      int j = col - 66;
      float s0 = PI_F*(b0 + 1.f), s1 = PI_F*(b1 + 1.f);
      float eq = s0*w1q[j] + s1*w1q[64 + j];
      float ev = s0*w1v[j] + s1*w1v[64 + j];
      vq = __cosf(eq); vv = __cosf(ev);
    }
    sfq_s[e*132 + col] = vq;
    sfvT_s[col*32 + e] = vv;
  }
  __syncthreads();

  // ---- Phase C: attention logits via folded kw/kb ----
  if (tid < 128) {
    const int e = tid >> 2, h = tid & 3;
    const int m = selm[e];
    const float* kwrow = kw + ((size_t)((b*M_ + m)*4 + h))*132;
    float accq = kb[(size_t)(b*M_ + m)*4 + h];
    const float4* kw4 = (const float4*)kwrow;
    const float4* sf4 = (const float4*)(sfq_s + e*132);
    for (int q = 0; q < 32; ++q) {
      float4 kv = kw4[q], sv = sf4[q];
      accq = fmaf(sv.x, kv.x, accq);
      accq = fmaf(sv.y, kv.y, accq);
      accq = fmaf(sv.z, kv.z, accq);
      accq = fmaf(sv.w, kv.w, accq);
    }
    accq += sfq_s[e*132 + 128]*kwrow[128] + sfq_s[e*132 + 129]*kwrow[129];
    const float gk = gkv[e];
    logits_s[tid] = accq - seld[e]/(gk*gk);
  }
  __syncthreads();   // sfq dead; buf reusable

  // ---- Phase D: GEMM1  [32 x 130] @ [130 x 256] -> b_v* | gterm ----
  const int er = tid & 7;    // 8 edge-groups of 4
  const int jc = tid >> 3;   // 32 col-groups of 8
  float acc[4][8];
#pragma unroll
  for (int i = 0; i < 4; ++i)
#pragma unroll
    for (int j = 0; j < 8; ++j) acc[i][j] = 0.f;

  for (int kt = 0; kt < 5; ++kt) {
    const int a0 = kt*32;
    const int ka = (kt == 4) ? 2 : 32;
    for (int i = tid; i < ka*64; i += 256)
      reinterpret_cast<float4*>(buf)[i] = reinterpret_cast<const float4*>(W2 + a0*256)[i];
    __syncthreads();
    for (int a2 = 0; a2 < ka; ++a2) {
      const int a = a0 + a2;
      float sv[4], w8[8];
      *reinterpret_cast<float4*>(sv)     = *reinterpret_cast<const float4*>(&sfvT_s[a*32 + er*4]);
      *reinterpret_cast<float4*>(w8)     = *reinterpret_cast<const float4*>(&buf[a2*256 + jc*8]);
      *reinterpret_cast<float4*>(w8 + 4) = *reinterpret_cast<const float4*>(&buf[a2*256 + jc*8 + 4]);
#pragma unroll
      for (int ee = 0; ee < 4; ++ee)
#pragma unroll
        for (int jj = 0; jj < 8; ++jj)
          acc[ee][jj] = fmaf(sv[ee], w8[jj], acc[ee][jj]);
    }
    __syncthreads();
  }

  // ---- Phase D epilogue: evecT = vf * b_v_acc ; tpart = gterm + base + cgv ----
  float* evecT = sfvT_s;   // [128][32]
  float* tpart = buf;      // [32][128]
  if (jc < 16) {
#pragma unroll
    for (int ee = 0; ee < 4; ++ee) {
      const int e = er*4 + ee;
      const float* vrow = vf + ((size_t)(b*M_ + selm[e]))*NH_ + jc*8;
#pragma unroll
      for (int jj = 0; jj < 8; ++jj)
        evecT[(jc*8 + jj)*32 + e] = vrow[jj] * acc[ee][jj];
    }
  } else {
    const int j2b = (jc - 16)*8;
#pragma unroll
    for (int ee = 0; ee < 4; ++ee) {
      const int e = er*4 + ee;
      const float* brow = base + ((size_t)(b*M_ + selm[e]))*NH_ + j2b;
#pragma unroll
      for (int jj = 0; jj < 8; ++jj)
        tpart[e*NH_ + j2b + jj] = acc[ee][jj] + brow[jj] + cgv[j2b + jj];
    }
  }
  __syncthreads();

  // ---- Phase E: GEMM2  [32 x 128] @ wv1[128 x 128], add tpart, gelu ----
  float acc2[4][4];
#pragma unroll
  for (int i = 0; i < 4; ++i)
#pragma unroll
    for (int j = 0; j < 4; ++j) acc2[i][j] = 0.f;
  float* wtile = buf + 32*NH_;  // second half of buf
  for (int kt = 0; kt < 4; ++kt) {
    for (int i = tid; i < 32*NH_/4; i += 256)
      reinterpret_cast<float4*>(wtile)[i] = reinterpret_cast<const float4*>(wv1 + kt*32*NH_)[i];
    __syncthreads();
    for (int i2 = 0; i2 < 32; ++i2) {
      const int i = kt*32 + i2;
      float ev[4], wr[4];
      *reinterpret_cast<float4*>(ev) = *reinterpret_cast<const float4*>(&evecT[i*32 + er*4]);
      *reinterpret_cast<float4*>(wr) = *reinterpret_cast<const float4*>(&wtile[i2*NH_ + jc*4]);
#pragma unroll
      for (int ee = 0; ee < 4; ++ee)
#pragma unroll
        for (int jj = 0; jj < 4; ++jj)
          acc2[ee][jj] = fmaf(ev[ee], wr[jj], acc2[ee][jj]);
    }
    __syncthreads();
  }
#pragma unroll
  for (int ee = 0; ee < 4; ++ee) {
    const int e = er*4 + ee;
#pragma unroll
    for (int jj = 0; jj < 4; ++jj) {
      const int j = jc*4 + jj;
      float tval = acc2[ee][jj] + tpart[e*NH_ + j];
      // tanh-approx gelu (jax default)
      float u = 0.79788456080286536f*(tval + 0.044715f*tval*tval*tval);
      float ex = __expf(2.f*u);
      float th = 1.f - 2.f/(ex + 1.f);
      tpart[e*NH_ + j] = 0.5f*tval*(1.f + th);   // in-place: same owner thread
    }
  }
  __syncthreads();

  // ---- Phase F: po[e][12] = gt[e] @ wvoT ----
  const float* gt = buf;
  for (int t = tid; t < K_*12; t += 256) {
    const int e = t / 12, r = t - (t/12)*12;
    const float4* wr4 = reinterpret_cast<const float4*>(wvoT + r*NH_);
    const float4* gr4 = reinterpret_cast<const float4*>(gt + e*NH_);
    float a0 = 0.f, a1 = 0.f, a2 = 0.f, a3 = 0.f;
    for (int q = 0; q < NH_/4; ++q) {
      float4 wq = wr4[q], gq = gr4[q];
      a0 = fmaf(gq.x, wq.x, a0);
      a1 = fmaf(gq.y, wq.y, a1);
      a2 = fmaf(gq.z, wq.z, a2);
      a3 = fmaf(gq.w, wq.w, a3);
    }
    poL[t] = (a0 + a1) + (a2 + a3);
  }
  __syncthreads();

  // ---- Phase G: softmax over K per head, combine, write out ----
  if (tid < HEADS_) {
    const int h = tid;
    float mx = -3.4e38f;
    for (int e = 0; e < K_; ++e) mx = fmaxf(mx, logits_s[e*4 + h]);
    float s = 0.f;
    for (int e = 0; e < K_; ++e) {
      float w = __expf(logits_s[e*4 + h] - mx);
      wts[e*4 + h] = w; s += w;
    }
    swt[h] = s;
  }
  __syncthreads();
  if (tid < 3) {
    float accv = outconst[tid];
    for (int e = 0; e < K_; ++e)
      for (int h = 0; h < HEADS_; ++h)
        accv = fmaf(wts[e*4 + h]/swt[h], poL[e*12 + h*3 + tid], accv);
    out[(size_t)bn*3 + tid] = accv;
  }
}

extern "C" void kernel_launch(void* const* d_in, const int* in_sizes, int n_in,
                              void* d_out, int out_size, void* d_ws, size_t ws_size,
                              hipStream_t stream) {
  (void)in_sizes; (void)n_in; (void)out_size; (void)ws_size;
  const float* x    = (const float*)d_in[0];
  const float* p    = (const float*)d_in[1];
  const float* c    = (const float*)d_in[2];
  const float* g    = (const float*)d_in[3];
  const float* w1q  = (const float*)d_in[4];
  const float* w2q  = (const float*)d_in[5];
  const float* b2q  = (const float*)d_in[6];
  const float* w3q  = (const float*)d_in[7];
  const float* b3q  = (const float*)d_in[8];
  const float* w1v  = (const float*)d_in[9];
  const float* w2v  = (const float*)d_in[10];
  const float* b2v  = (const float*)d_in[11];
  const float* w3v  = (const float*)d_in[12];
  const float* b3v  = (const float*)d_in[13];
  const float* wk   = (const float*)d_in[14];
  const float* bk   = (const float*)d_in[15];
  const float* wvw  = (const float*)d_in[16];
  const float* bv   = (const float*)d_in[17];
  const float* wv1  = (const float*)d_in[18];
  const float* bv1  = (const float*)d_in[19];
  const float* wv2  = (const float*)d_in[20];
  const float* bv2  = (const float*)d_in[21];
  const float* wout = (const float*)d_in[22];
  const float* bout = (const float*)d_in[23];
  float* ws = (float*)d_ws;
  float* outp = (float*)d_out;

  hipLaunchKernelGGL(enf_wgw, dim3(64), dim3(256), 0, stream, w3v, wv1, ws + OFF_WGW);
  hipLaunchKernelGGL(enf_w2, dim3(130), dim3(256), 0, stream, w2v, w3v, ws + OFF_WGW, ws + OFF_W2);
  hipLaunchKernelGGL(enf_consts, dim3(1), dim3(256), 0, stream,
                     b2v, w3v, b3v, ws + OFF_WGW, wv1, bv1, wv2, wout, bv2, bout,
                     ws + OFF_CB, ws + OFF_CGV, ws + OFF_WVOT, ws + OFF_OUTC);
  hipLaunchKernelGGL(enf_latent, dim3(B_*M_), dim3(256), 0, stream,
                     c, wk, bk, wvw, bv, w3q, b3q, w2q, b2q, wv1, ws + OFF_CB,
                     ws + OFF_KW, ws + OFF_KB, ws + OFF_VF, ws + OFF_BASE);
  hipLaunchKernelGGL(enf_main, dim3(B_*N_), dim3(256), 0, stream,
                     x, p, g, w1q, w1v, ws + OFF_W2, wv1, ws + OFF_CGV,
                     ws + OFF_WVOT, ws + OFF_OUTC, ws + OFF_KW, ws + OFF_KB,
                     ws + OFF_VF, ws + OFF_BASE, outp);
}

// Round 2
// 845.787 us; speedup vs baseline: 1.5514x; 1.5514x over previous
//
#include <hip/hip_runtime.h>
#include <math.h>

#define B_ 4
#define N_ 2048
#define M_ 1024
#define K_ 32
#define HEADS_ 4
#define NH_ 128
#define PI_F 3.14159265358979323846f

typedef unsigned long long ull;

// workspace offsets (in floats)
#define OFF_WGW   0            // 128*128
#define OFF_W2    16384        // 130*256  [WB | WG]
#define OFF_CB    49664        // 128
#define OFF_CGV   49792        // 128
#define OFF_WVOT  49920        // 12*128
#define OFF_OUTC  51456        // 4
#define OFF_KW    51460        // B*M*4*132
#define OFF_KB    2214148      // B*M*4
#define OFF_VF    2230532      // B*M*128
#define OFF_BASE  2754820      // B*M*128

// ---------- precompute kernels ----------

__global__ void enf_wgw(const float* __restrict__ w3v, const float* __restrict__ wv1,
                        float* __restrict__ WGW) {
  int o = blockIdx.x * 256 + threadIdx.x;   // 16384
  int i = o >> 7, j = o & 127;
  float acc = 0.f;
  for (int r = 0; r < 128; ++r) acc = fmaf(w3v[i*256 + 128 + r], wv1[r*128 + j], acc);
  WGW[o] = acc;
}

__global__ void enf_w2(const float* __restrict__ w2v, const float* __restrict__ w3v,
                       const float* __restrict__ WGW, float* __restrict__ W2) {
  int a = blockIdx.x;       // 0..129
  int j = threadIdx.x;      // 0..255
  float acc = 0.f;
  if (j < 128) {
    for (int i = 0; i < 128; ++i) acc = fmaf(w2v[a*128 + i], w3v[i*256 + j], acc);
  } else {
    int j2 = j - 128;
    for (int i = 0; i < 128; ++i) acc = fmaf(w2v[a*128 + i], WGW[i*128 + j2], acc);
  }
  W2[a*256 + j] = acc;
}

__global__ void enf_consts(const float* __restrict__ b2v, const float* __restrict__ w3v,
                           const float* __restrict__ b3v, const float* __restrict__ WGW,
                           const float* __restrict__ wv1, const float* __restrict__ bv1,
                           const float* __restrict__ wv2, const float* __restrict__ wout,
                           const float* __restrict__ bv2, const float* __restrict__ bout,
                           float* __restrict__ cb, float* __restrict__ cgv,
                           float* __restrict__ wvoT, float* __restrict__ outconst) {
  int t = threadIdx.x;
  if (t < 128) {
    float a1 = 0.f;
    for (int i = 0; i < 128; ++i) a1 = fmaf(b2v[i], w3v[i*256 + t], a1);
    cb[t] = a1 + b3v[t];
    float a2 = 0.f;
    for (int i = 0; i < 128; ++i) a2 = fmaf(b2v[i], WGW[i*128 + t], a2);
    for (int r = 0; r < 128; ++r) a2 = fmaf(b3v[128 + r], wv1[r*128 + t], a2);
    cgv[t] = a2 + bv1[t];
  }
  for (int o = t; o < 1536; o += 256) {
    int r12 = o >> 7, i = o & 127;
    int h = r12 / 3, c = r12 - h*3;
    float acc = 0.f;
    for (int k = 0; k < 128; ++k)
      acc = fmaf(wv2[i*512 + h*128 + k], wout[(h*128 + k)*3 + c], acc);
    wvoT[r12*128 + i] = acc;
  }
  if (t < 3) {
    float acc = bout[t];
    for (int r = 0; r < 512; ++r) acc = fmaf(bv2[r], wout[r*3 + t], acc);
    outconst[t] = acc;
  }
}

// per-(b,m): vf, base, kw, kb
__global__ __launch_bounds__(256) void enf_latent(
    const float* __restrict__ c, const float* __restrict__ wk, const float* __restrict__ bk,
    const float* __restrict__ wvw, const float* __restrict__ bv,
    const float* __restrict__ w3q, const float* __restrict__ b3q,
    const float* __restrict__ w2q, const float* __restrict__ b2q,
    const float* __restrict__ wv1, const float* __restrict__ cb,
    float* __restrict__ kw, float* __restrict__ kb,
    float* __restrict__ vf_o, float* __restrict__ base_o) {
  const int bm = blockIdx.x;
  const int tid = threadIdx.x;
  __shared__ float cl[128];
  __shared__ float kfl[256];
  __shared__ float vfl[128];
  __shared__ float kql[4*128];
  if (tid < 128) cl[tid] = c[(size_t)bm*128 + tid];
  __syncthreads();
  { // kf
    int j = tid;
    float acc = bk[j];
    for (int l = 0; l < 128; ++l) acc = fmaf(cl[l], wk[l*256 + j], acc);
    kfl[j] = acc;
  }
  if (tid < 128) { // vf
    int j = tid;
    float acc = bv[j];
    for (int l = 0; l < 128; ++l) acc = fmaf(cl[l], wvw[l*128 + j], acc);
    vfl[j] = acc;
    vf_o[(size_t)bm*128 + j] = acc;
  }
  __syncthreads();
  for (int t = tid; t < 512; t += 256) {
    int h = t >> 7, j = t & 127;
    const float* wr = w3q + j*256 + h*64;
    const float* kfh = kfl + h*64;
    float acc = 0.f;
    for (int a = 0; a < 64; ++a) acc = fmaf(wr[a], kfh[a], acc);
    kql[h*128 + j] = acc;
  }
  if (tid < 128) { // base = (vf*(1+cb)) @ wv1
    int j = tid;
    float acc = 0.f;
    for (int i = 0; i < 128; ++i) acc = fmaf(vfl[i]*(1.f + cb[i]), wv1[i*128 + j], acc);
    base_o[(size_t)bm*128 + j] = acc;
  }
  __syncthreads();
  for (int t = tid; t < 520; t += 256) {
    int a = t >> 2, h = t & 3;
    const float* w2r = w2q + a*128;
    const float* kqh = kql + h*128;
    float acc = 0.f;
    for (int j = 0; j < 128; ++j) acc = fmaf(w2r[j], kqh[j], acc);
    kw[((size_t)bm*4 + h)*132 + a] = acc;
  }
  if (tid < 8)   // zero pad cols 130,131 so float4-dot tail is exact
    kw[((size_t)bm*4 + (tid & 3))*132 + 130 + (tid >> 2)] = 0.f;
  if (tid < 4) {
    int h = tid;
    float acc = 0.f;
    for (int j = 0; j < 128; ++j) acc = fmaf(b2q[j], kql[h*128 + j], acc);
    for (int a = 0; a < 64; ++a) acc = fmaf(b3q[h*64 + a], kfl[h*64 + a], acc);
    kb[(size_t)bm*4 + h] = acc;
  }
}

// ---------- main kernel: one block per (b,n) ----------
__global__ __launch_bounds__(256) void enf_main(
    const float* __restrict__ x, const float* __restrict__ p,
    const float* __restrict__ g,
    const float* __restrict__ w1q, const float* __restrict__ w1v,
    const float* __restrict__ W2, const float* __restrict__ wv1,
    const float* __restrict__ cgv, const float* __restrict__ wvoT,
    const float* __restrict__ outconst,
    const float* __restrict__ kw, const float* __restrict__ kb,
    const float* __restrict__ vf, const float* __restrict__ base,
    float* __restrict__ out) {
  const int bn = blockIdx.x;
  const int b = bn >> 11;          // N = 2048
  const int tid = threadIdx.x;
  const int lane = tid & 63;
  const int wid = tid >> 6;

  __shared__ alignas(16) float r1[130*32];   // sfvT[130][32] -> evecT[128][32]
  __shared__ alignas(16) float r2[132*32];   // sfqT[132][32] -> tpart/gt[32][128]
  __shared__ ull   candk[128];
  __shared__ int   selm[K_];
  __shared__ float seld[K_];
  __shared__ float gkv[K_];
  __shared__ float bi0[K_], bi1[K_];
  __shared__ float logits_s[K_*HEADS_];
  __shared__ alignas(16) float poL[K_*12];
  __shared__ float hpart[HEADS_*4];

  const float x0 = x[bn*2 + 0];
  const float x1 = x[bn*2 + 1];
  const float2* pb2 = (const float2*)(p + (size_t)b*M_*2);

  // ---- Phase A: per-wave top-32 via 64-bit (dist,m) lexicographic keys ----
  ull kl[4];
#pragma unroll
  for (int s = 0; s < 4; ++s) {
    int m = wid*256 + s*64 + lane;
    float2 pv = pb2[m];
    float d0 = x0 - pv.x, d1 = x1 - pv.y;
    // match reference rounding exactly: round each square, then add
    float d = __fadd_rn(__fmul_rn(d0, d0), __fmul_rn(d1, d1));
    kl[s] = ((ull)__float_as_uint(d) << 32) | (unsigned)m;
  }
  for (int it = 0; it < K_; ++it) {
    ull k01 = kl[0] < kl[1] ? kl[0] : kl[1];
    ull k23 = kl[2] < kl[3] ? kl[2] : kl[3];
    ull k = k01 < k23 ? k01 : k23;
#pragma unroll
    for (int off = 1; off < 64; off <<= 1) {
      ull o = __shfl_xor(k, off);
      k = o < k ? o : k;
    }
    if (lane == 0) candk[wid*K_ + it] = k;
#pragma unroll
    for (int s = 0; s < 4; ++s) if (kl[s] == k) kl[s] = ~0ull;
  }
  __syncthreads();
  // merge 128 candidates -> exact global top-32 by rank (keys unique)
  if (tid < 128) {
    ull k = candk[tid];
    int rank = 0;
    for (int i = 0; i < 128; ++i) rank += (candk[i] < k) ? 1 : 0;
    if (rank < K_) {
      selm[rank] = (int)(unsigned)(k & 0xffffffffull);
      seld[rank] = __uint_as_float((unsigned)(k >> 32));
    }
  }
  __syncthreads();
  if (tid < K_) {
    int m = selm[tid];
    gkv[tid] = g[(size_t)b*M_ + m];
    float2 pv = pb2[m];
    bi0[tid] = x0 - pv.x;
    bi1[tid] = x1 - pv.y;
  }
  __syncthreads();

  // ---- Phase B: sin features, both transposed [col][32] ----
  float* sfqT = r2;
  float* sfvT = r1;
  if (tid < 64) {
    int e = tid & 31, cc = tid >> 5;
    float v = __sinf(cc ? bi1[e] : bi0[e]);
    sfqT[cc*32 + e] = v;
    sfvT[cc*32 + e] = v;
    sfqT[(130 + cc)*32 + e] = 0.f;   // zero pad rows 130,131 for float4 tail
  }
  {
    const int e = tid & 31;
    const float b0 = bi0[e], b1 = bi1[e];
    const float s0 = PI_F*(b0 + 1.f), s1 = PI_F*(b1 + 1.f);
    for (int j = tid >> 5; j < 64; j += 8) {
      float eq = s0*w1q[j] + s1*w1q[64 + j];
      sfqT[(2 + j)*32 + e]  = __sinf(eq);
      sfqT[(66 + j)*32 + e] = __cosf(eq);
      float ev = s0*w1v[j] + s1*w1v[64 + j];
      sfvT[(2 + j)*32 + e]  = __sinf(ev);
      sfvT[(66 + j)*32 + e] = __cosf(ev);
    }
  }
  __syncthreads();

  // ---- Phase C (tid<128) + Phase D (all threads), no barrier between ----
  if (tid < 128) {
    const int e = tid >> 2, h = tid & 3;
    const int m = selm[e];
    const float* kwrow = kw + ((size_t)((b*M_ + m)*4 + h))*132;
    float accq = kb[(size_t)(b*M_ + m)*4 + h];
    const float4* kw4 = (const float4*)kwrow;
#pragma unroll 4
    for (int q4 = 0; q4 < 33; ++q4) {
      float4 kv = kw4[q4];
      int q = q4*4;
      accq = fmaf(sfqT[q*32 + e],       kv.x, accq);
      accq = fmaf(sfqT[(q + 1)*32 + e], kv.y, accq);
      accq = fmaf(sfqT[(q + 2)*32 + e], kv.z, accq);
      accq = fmaf(sfqT[(q + 3)*32 + e], kv.w, accq);
    }
    const float gk = gkv[e];
    logits_s[tid] = accq - seld[e]/(gk*gk);
  }

  // ---- Phase D: GEMM1  sfv[32x130] @ W2[130x256], W2 direct from global ----
  const int er = tid & 7;    // 8 edge-groups of 4
  const int jc = tid >> 3;   // 32 col-groups of 8
  float acc[4][8];
#pragma unroll
  for (int i = 0; i < 4; ++i)
#pragma unroll
    for (int j = 0; j < 8; ++j) acc[i][j] = 0.f;

#pragma unroll 2
  for (int a = 0; a < 130; ++a) {
    float4 sv4 = *(const float4*)&sfvT[a*32 + er*4];
    const float* w2r = W2 + a*256 + jc*8;
    float4 wA = *(const float4*)w2r;
    float4 wB = *(const float4*)(w2r + 4);
    float sv[4] = {sv4.x, sv4.y, sv4.z, sv4.w};
    float w8[8] = {wA.x, wA.y, wA.z, wA.w, wB.x, wB.y, wB.z, wB.w};
#pragma unroll
    for (int ee = 0; ee < 4; ++ee)
#pragma unroll
      for (int jj = 0; jj < 8; ++jj)
        acc[ee][jj] = fmaf(sv[ee], w8[jj], acc[ee][jj]);
  }
  __syncthreads();   // all sfvT reads done; r1 reusable

  // ---- Phase D epilogue: evecT[j][e] = vf*b_v ; tpart[e][j] = gterm+base+cgv ----
  float* evecT = r1;   // [128][32]
  float* tpart = r2;   // [32][128]
  if (jc < 16) {
    float vv[4][8];
#pragma unroll
    for (int ee = 0; ee < 4; ++ee) {
      const float* vrow = vf + ((size_t)(b*M_ + selm[er*4 + ee]))*NH_ + jc*8;
      float4 a4 = *(const float4*)vrow;
      float4 b4 = *(const float4*)(vrow + 4);
      vv[ee][0]=a4.x; vv[ee][1]=a4.y; vv[ee][2]=a4.z; vv[ee][3]=a4.w;
      vv[ee][4]=b4.x; vv[ee][5]=b4.y; vv[ee][6]=b4.z; vv[ee][7]=b4.w;
    }
#pragma unroll
    for (int jj = 0; jj < 8; ++jj) {
      float4 w;
      w.x = vv[0][jj]*acc[0][jj];
      w.y = vv[1][jj]*acc[1][jj];
      w.z = vv[2][jj]*acc[2][jj];
      w.w = vv[3][jj]*acc[3][jj];
      *(float4*)&evecT[(jc*8 + jj)*32 + er*4] = w;
    }
  } else {
    const int j0 = (jc - 16)*8;
    float4 c0 = *(const float4*)(cgv + j0);
    float4 c1 = *(const float4*)(cgv + j0 + 4);
#pragma unroll
    for (int ee = 0; ee < 4; ++ee) {
      const int e = er*4 + ee;
      const float* brow = base + ((size_t)(b*M_ + selm[e]))*NH_ + j0;
      float4 b4 = *(const float4*)brow;
      float4 b5 = *(const float4*)(brow + 4);
      float4 t0, t1;
      t0.x = acc[ee][0] + b4.x + c0.x;
      t0.y = acc[ee][1] + b4.y + c0.y;
      t0.z = acc[ee][2] + b4.z + c0.z;
      t0.w = acc[ee][3] + b4.w + c0.w;
      t1.x = acc[ee][4] + b5.x + c1.x;
      t1.y = acc[ee][5] + b5.y + c1.y;
      t1.z = acc[ee][6] + b5.z + c1.z;
      t1.w = acc[ee][7] + b5.w + c1.w;
      *(float4*)&tpart[e*NH_ + j0] = t0;
      *(float4*)&tpart[e*NH_ + j0 + 4] = t1;
    }
  }
  __syncthreads();

  // ---- Phase E: GEMM2  ev[32x128] @ wv1[128x128] (global), +tpart, gelu ----
  float acc2[4][4];
#pragma unroll
  for (int i = 0; i < 4; ++i)
#pragma unroll
    for (int j = 0; j < 4; ++j) acc2[i][j] = 0.f;
#pragma unroll 4
  for (int i = 0; i < 128; ++i) {
    float4 ev4 = *(const float4*)&evecT[i*32 + er*4];
    float4 wr4 = *(const float4*)&wv1[i*128 + jc*4];
    float evv[4] = {ev4.x, ev4.y, ev4.z, ev4.w};
    float wr[4]  = {wr4.x, wr4.y, wr4.z, wr4.w};
#pragma unroll
    for (int ee = 0; ee < 4; ++ee)
#pragma unroll
      for (int jj = 0; jj < 4; ++jj)
        acc2[ee][jj] = fmaf(evv[ee], wr[jj], acc2[ee][jj]);
  }
#pragma unroll
  for (int ee = 0; ee < 4; ++ee) {
    const int e = er*4 + ee;
    float4 tp = *(const float4*)&tpart[e*NH_ + jc*4];
    float tv[4] = {tp.x, tp.y, tp.z, tp.w};
    float4 gv;
    float* gvp = &gv.x;
#pragma unroll
    for (int jj = 0; jj < 4; ++jj) {
      float tval = acc2[ee][jj] + tv[jj];
      float u = 0.79788456080286536f*(tval + 0.044715f*tval*tval*tval);
      float ex = __expf(2.f*u);
      float th = 1.f - 2.f/(ex + 1.f);
      gvp[jj] = 0.5f*tval*(1.f + th);
    }
    *(float4*)&tpart[e*NH_ + jc*4] = gv;   // in-place, same owner
  }
  __syncthreads();

  // ---- Phase F: po[e][12] = gt[e] @ wvoT^T ----
  const float* gt = r2;
  for (int t = tid; t < K_*12; t += 256) {
    const int e = t / 12, r = t - (t/12)*12;
    const float4* wr4 = (const float4*)(wvoT + r*NH_);
    const float4* gr4 = (const float4*)(gt + e*NH_);
    float a0 = 0.f, a1 = 0.f, a2 = 0.f, a3 = 0.f;
#pragma unroll 4
    for (int q = 0; q < NH_/4; ++q) {
      float4 wq = wr4[q], gq = gr4[q];
      a0 = fmaf(gq.x, wq.x, a0);
      a1 = fmaf(gq.y, wq.y, a1);
      a2 = fmaf(gq.z, wq.z, a2);
      a3 = fmaf(gq.w, wq.w, a3);
    }
    poL[t] = (a0 + a1) + (a2 + a3);
  }
  __syncthreads();

  // ---- Phase G: softmax over K per head + combine (wave-parallel) ----
  if (tid < 128) {
    const int h = tid >> 5, e = tid & 31;
    float l = logits_s[e*4 + h];
    float mx = l;
#pragma unroll
    for (int off = 1; off < 32; off <<= 1) mx = fmaxf(mx, __shfl_xor(mx, off));
    float w = __expf(l - mx);
    float s = w;
#pragma unroll
    for (int off = 1; off < 32; off <<= 1) s += __shfl_xor(s, off);
    float att = w / s;
    float p0 = att * poL[e*12 + h*3 + 0];
    float p1 = att * poL[e*12 + h*3 + 1];
    float p2 = att * poL[e*12 + h*3 + 2];
#pragma unroll
    for (int off = 1; off < 32; off <<= 1) {
      p0 += __shfl_xor(p0, off);
      p1 += __shfl_xor(p1, off);
      p2 += __shfl_xor(p2, off);
    }
    if (e == 0) { hpart[h*4 + 0] = p0; hpart[h*4 + 1] = p1; hpart[h*4 + 2] = p2; }
  }
  __syncthreads();
  if (tid < 3) {
    out[(size_t)bn*3 + tid] = outconst[tid]
        + hpart[0*4 + tid] + hpart[1*4 + tid] + hpart[2*4 + tid] + hpart[3*4 + tid];
  }
}

extern "C" void kernel_launch(void* const* d_in, const int* in_sizes, int n_in,
                              void* d_out, int out_size, void* d_ws, size_t ws_size,
                              hipStream_t stream) {
  (void)in_sizes; (void)n_in; (void)out_size; (void)ws_size;
  const float* x    = (const float*)d_in[0];
  const float* p    = (const float*)d_in[1];
  const float* c    = (const float*)d_in[2];
  const float* g    = (const float*)d_in[3];
  const float* w1q  = (const float*)d_in[4];
  const float* w2q  = (const float*)d_in[5];
  const float* b2q  = (const float*)d_in[6];
  const float* w3q  = (const float*)d_in[7];
  const float* b3q  = (const float*)d_in[8];
  const float* w1v  = (const float*)d_in[9];
  const float* w2v  = (const float*)d_in[10];
  const float* b2v  = (const float*)d_in[11];
  const float* w3v  = (const float*)d_in[12];
  const float* b3v  = (const float*)d_in[13];
  const float* wk   = (const float*)d_in[14];
  const float* bk   = (const float*)d_in[15];
  const float* wvw  = (const float*)d_in[16];
  const float* bv   = (const float*)d_in[17];
  const float* wv1  = (const float*)d_in[18];
  const float* bv1  = (const float*)d_in[19];
  const float* wv2  = (const float*)d_in[20];
  const float* bv2  = (const float*)d_in[21];
  const float* wout = (const float*)d_in[22];
  const float* bout = (const float*)d_in[23];
  float* ws = (float*)d_ws;
  float* outp = (float*)d_out;

  hipLaunchKernelGGL(enf_wgw, dim3(64), dim3(256), 0, stream, w3v, wv1, ws + OFF_WGW);
  hipLaunchKernelGGL(enf_w2, dim3(130), dim3(256), 0, stream, w2v, w3v, ws + OFF_WGW, ws + OFF_W2);
  hipLaunchKernelGGL(enf_consts, dim3(1), dim3(256), 0, stream,
                     b2v, w3v, b3v, ws + OFF_WGW, wv1, bv1, wv2, wout, bv2, bout,
                     ws + OFF_CB, ws + OFF_CGV, ws + OFF_WVOT, ws + OFF_OUTC);
  hipLaunchKernelGGL(enf_latent, dim3(B_*M_), dim3(256), 0, stream,
                     c, wk, bk, wvw, bv, w3q, b3q, w2q, b2q, wv1, ws + OFF_CB,
                     ws + OFF_KW, ws + OFF_KB, ws + OFF_VF, ws + OFF_BASE);
  hipLaunchKernelGGL(enf_main, dim3(B_*N_), dim3(256), 0, stream,
                     x, p, g, w1q, w1v, ws + OFF_W2, wv1, ws + OFF_CGV,
                     ws + OFF_WVOT, ws + OFF_OUTC, ws + OFF_KW, ws + OFF_KB,
                     ws + OFF_VF, ws + OFF_BASE, outp);
}

// Round 3
// 558.917 us; speedup vs baseline: 2.3477x; 1.5133x over previous
//
#include <hip/hip_runtime.h>
#include <math.h>

#define B_ 4
#define N_ 2048
#define M_ 1024
#define K_ 32
#define HEADS_ 4
#define NH_ 128
#define PI_F 3.14159265358979323846f

typedef unsigned long long ull;
typedef __attribute__((ext_vector_type(8))) _Float16 half8;
typedef __attribute__((ext_vector_type(4))) _Float16 half4v;
typedef __attribute__((ext_vector_type(4))) float f32x4;

// workspace offsets (in floats)
#define OFF_WGW   0            // 128*128
#define OFF_W2    16384        // 130*256  [WB | WG]
#define OFF_CB    49664        // 128
#define OFF_CGV   49792        // 128
#define OFF_WVOT  49920        // 12*128
#define OFF_OUTC  51456        // 4
#define OFF_KW    51460        // B*M*4*132
#define OFF_KB    2214148      // B*M*4
#define OFF_VF    2230532      // B*M*128
#define OFF_BASE  2754820      // B*M*128
#define OFF_W2F   3279108      // 40960 halfs = 20480 floats (W2^T MFMA A-frags)
#define OFF_WV1F  3299588      // 16384 halfs = 8192 floats  (wv1^T MFMA A-frags)
// total = 3307780 floats (~13.2 MB)

// ---------- precompute kernels ----------

__global__ void enf_wgw(const float* __restrict__ w3v, const float* __restrict__ wv1,
                        float* __restrict__ WGW) {
  int o = blockIdx.x * 256 + threadIdx.x;   // 16384
  int i = o >> 7, j = o & 127;
  float acc = 0.f;
  for (int r = 0; r < 128; ++r) acc = fmaf(w3v[i*256 + 128 + r], wv1[r*128 + j], acc);
  WGW[o] = acc;
}

__global__ void enf_w2(const float* __restrict__ w2v, const float* __restrict__ w3v,
                       const float* __restrict__ WGW, float* __restrict__ W2) {
  int a = blockIdx.x;       // 0..129
  int j = threadIdx.x;      // 0..255
  float acc = 0.f;
  if (j < 128) {
    for (int i = 0; i < 128; ++i) acc = fmaf(w2v[a*128 + i], w3v[i*256 + j], acc);
  } else {
    int j2 = j - 128;
    for (int i = 0; i < 128; ++i) acc = fmaf(w2v[a*128 + i], WGW[i*128 + j2], acc);
  }
  W2[a*256 + j] = acc;
}

// W2^T A-fragments for mfma_f32_16x16x32_f16: layout [mt(16)][ks(5)][lane(64)][i(8)]
// A[row = n = mt*16 + (lane&15)][k = ks*32 + ((lane>>4)<<3) + i] = W2[k][n]
__global__ void enf_w2frag(const float* __restrict__ W2, _Float16* __restrict__ W2f) {
  int idx = blockIdx.x * 256 + threadIdx.x;   // 40960
  if (idx >= 40960) return;
  int i = idx & 7, lane = (idx >> 3) & 63;
  int rest = idx >> 9;            // mt*5 + ks
  int ks = rest % 5, mt = rest / 5;
  int k = ks*32 + ((lane >> 4) << 3) + i;
  int n = mt*16 + (lane & 15);
  W2f[idx] = (k < 130) ? (_Float16)W2[k*256 + n] : (_Float16)0.f;
}

// wv1^T A-fragments: [mt(8)][ks(4)][lane(64)][i(8)];  A[j][k] = wv1[k][j]
__global__ void enf_wv1frag(const float* __restrict__ wv1, _Float16* __restrict__ wv1f) {
  int idx = blockIdx.x * 256 + threadIdx.x;   // 16384
  if (idx >= 16384) return;
  int i = idx & 7, lane = (idx >> 3) & 63;
  int rest = idx >> 9;            // mt*4 + ks
  int ks = rest & 3, mt = rest >> 2;
  int k = ks*32 + ((lane >> 4) << 3) + i;
  int j = mt*16 + (lane & 15);
  wv1f[idx] = (_Float16)wv1[k*128 + j];
}

__global__ void enf_consts(const float* __restrict__ b2v, const float* __restrict__ w3v,
                           const float* __restrict__ b3v, const float* __restrict__ WGW,
                           const float* __restrict__ wv1, const float* __restrict__ bv1,
                           const float* __restrict__ wv2, const float* __restrict__ wout,
                           const float* __restrict__ bv2, const float* __restrict__ bout,
                           float* __restrict__ cb, float* __restrict__ cgv,
                           float* __restrict__ wvoT, float* __restrict__ outconst) {
  int t = threadIdx.x;
  if (t < 128) {
    float a1 = 0.f;
    for (int i = 0; i < 128; ++i) a1 = fmaf(b2v[i], w3v[i*256 + t], a1);
    cb[t] = a1 + b3v[t];
    float a2 = 0.f;
    for (int i = 0; i < 128; ++i) a2 = fmaf(b2v[i], WGW[i*128 + t], a2);
    for (int r = 0; r < 128; ++r) a2 = fmaf(b3v[128 + r], wv1[r*128 + t], a2);
    cgv[t] = a2 + bv1[t];
  }
  for (int o = t; o < 1536; o += 256) {
    int r12 = o >> 7, i = o & 127;
    int h = r12 / 3, c = r12 - h*3;
    float acc = 0.f;
    for (int k = 0; k < 128; ++k)
      acc = fmaf(wv2[i*512 + h*128 + k], wout[(h*128 + k)*3 + c], acc);
    wvoT[r12*128 + i] = acc;
  }
  if (t < 3) {
    float acc = bout[t];
    for (int r = 0; r < 512; ++r) acc = fmaf(bv2[r], wout[r*3 + t], acc);
    outconst[t] = acc;
  }
}

// per-(b,m): vf, base, kw, kb
__global__ __launch_bounds__(256) void enf_latent(
    const float* __restrict__ c, const float* __restrict__ wk, const float* __restrict__ bk,
    const float* __restrict__ wvw, const float* __restrict__ bv,
    const float* __restrict__ w3q, const float* __restrict__ b3q,
    const float* __restrict__ w2q, const float* __restrict__ b2q,
    const float* __restrict__ wv1, const float* __restrict__ cb,
    float* __restrict__ kw, float* __restrict__ kb,
    float* __restrict__ vf_o, float* __restrict__ base_o) {
  const int bm = blockIdx.x;
  const int tid = threadIdx.x;
  __shared__ float cl[128];
  __shared__ float kfl[256];
  __shared__ float vfl[128];
  __shared__ float kql[4*128];
  if (tid < 128) cl[tid] = c[(size_t)bm*128 + tid];
  __syncthreads();
  { // kf
    int j = tid;
    float acc = bk[j];
    for (int l = 0; l < 128; ++l) acc = fmaf(cl[l], wk[l*256 + j], acc);
    kfl[j] = acc;
  }
  if (tid < 128) { // vf
    int j = tid;
    float acc = bv[j];
    for (int l = 0; l < 128; ++l) acc = fmaf(cl[l], wvw[l*128 + j], acc);
    vfl[j] = acc;
    vf_o[(size_t)bm*128 + j] = acc;
  }
  __syncthreads();
  for (int t = tid; t < 512; t += 256) {
    int h = t >> 7, j = t & 127;
    const float* wr = w3q + j*256 + h*64;
    const float* kfh = kfl + h*64;
    float acc = 0.f;
    for (int a = 0; a < 64; ++a) acc = fmaf(wr[a], kfh[a], acc);
    kql[h*128 + j] = acc;
  }
  if (tid < 128) { // base = (vf*(1+cb)) @ wv1
    int j = tid;
    float acc = 0.f;
    for (int i = 0; i < 128; ++i) acc = fmaf(vfl[i]*(1.f + cb[i]), wv1[i*128 + j], acc);
    base_o[(size_t)bm*128 + j] = acc;
  }
  __syncthreads();
  for (int t = tid; t < 520; t += 256) {
    int a = t >> 2, h = t & 3;
    const float* w2r = w2q + a*128;
    const float* kqh = kql + h*128;
    float acc = 0.f;
    for (int j = 0; j < 128; ++j) acc = fmaf(w2r[j], kqh[j], acc);
    kw[((size_t)bm*4 + h)*132 + a] = acc;
  }
  if (tid < 8)
    kw[((size_t)bm*4 + (tid & 3))*132 + 130 + (tid >> 2)] = 0.f;
  if (tid < 4) {
    int h = tid;
    float acc = 0.f;
    for (int j = 0; j < 128; ++j) acc = fmaf(b2q[j], kql[h*128 + j], acc);
    for (int a = 0; a < 64; ++a) acc = fmaf(b3q[h*64 + a], kfl[h*64 + a], acc);
    kb[(size_t)bm*4 + h] = acc;
  }
}

// sfv B-fragment position: [nt(2)][ks(5)][lane(64)][i(8)] halfs
__device__ __forceinline__ int fragpos(int k, int e) {
  return ((((e >> 4)*5 + (k >> 5))*64 + (((k >> 3) & 3) << 4) + (e & 15)) << 3) + (k & 7);
}

// ---------- main kernel: one block per (b,n) ----------
__global__ __launch_bounds__(256, 4) void enf_main(
    const float* __restrict__ x, const float* __restrict__ p,
    const float* __restrict__ g,
    const float* __restrict__ w1q, const float* __restrict__ w1v,
    const _Float16* __restrict__ w2f, const _Float16* __restrict__ wv1f,
    const float* __restrict__ cgv, const float* __restrict__ wvoT,
    const float* __restrict__ outconst,
    const float* __restrict__ kw, const float* __restrict__ kb,
    const float* __restrict__ vf, const float* __restrict__ base,
    float* __restrict__ out) {
  const int bn = blockIdx.x;
  const int b = bn >> 11;          // N = 2048
  const int tid = threadIdx.x;
  const int lane = tid & 63;
  const int wid = tid >> 6;

  // region1: sfq fp32 [132][32]; aliases: candd/candm (A), evlds half[32][136]@0, poL@float 3072 (F)
  __shared__ alignas(16) float r1[4224];
  // region2: sfvB frags (5120 halfs, B..GEMM1); alias tpart fp32 [32][132] (epilogue..F)
  __shared__ alignas(16) float r2[4224];
  __shared__ int   selm[K_];
  __shared__ float seld[K_];
  __shared__ float gkv[K_];
  __shared__ float bi0[K_], bi1[K_];
  __shared__ float logits_s[K_*HEADS_];
  __shared__ float hpart[HEADS_*4];

  float* candd = r1;
  int*   candm = (int*)(r1 + 128);
  float* sfq   = r1;                       // [132][32]
  _Float16* evlds = (_Float16*)r1;         // [32][136]
  float* poL   = r1 + 3072;                // [32][12]
  _Float16* sfvB = (_Float16*)r2;          // 5120 halfs
  float* tpart = r2;                       // [32][132]

  const float x0 = x[bn*2 + 0];
  const float x1 = x[bn*2 + 1];
  const float2* pb2 = (const float2*)(p + (size_t)b*M_*2);

  // ---- Phase A: per-wave top-32, 32-bit dist keys + ballot owner ----
  float dl[4];
#pragma unroll
  for (int s = 0; s < 4; ++s) {
    int m = wid*256 + s*64 + lane;
    float2 pv = pb2[m];
    float d0 = x0 - pv.x, d1 = x1 - pv.y;
    dl[s] = __fadd_rn(__fmul_rn(d0, d0), __fmul_rn(d1, d1));
  }
  for (int it = 0; it < K_; ++it) {
    float md = fminf(fminf(dl[0], dl[1]), fminf(dl[2], dl[3]));
#pragma unroll
    for (int off = 1; off < 64; off <<= 1) md = fminf(md, __shfl_xor(md, off));
    ull vote = __ballot(dl[0] == md || dl[1] == md || dl[2] == md || dl[3] == md);
    int owner = __ffsll(vote) - 1;
    if (lane == owner) {
      int s = (dl[0] == md) ? 0 : (dl[1] == md) ? 1 : (dl[2] == md) ? 2 : 3;
      candd[wid*K_ + it] = md;
      candm[wid*K_ + it] = wid*256 + s*64 + lane;
      dl[s] = 3.4e38f;
    }
  }
  __syncthreads();
  // merge 128 candidates -> exact global top-32 (rank; ties by candidate idx)
  if (tid < 128) {
    float d = candd[tid];
    int m = candm[tid];
    int rank = 0;
    for (int i = 0; i < 128; ++i) {
      float di = candd[i];
      rank += (di < d || (di == d && i < tid)) ? 1 : 0;
    }
    if (rank < K_) { selm[rank] = m; seld[rank] = d; }
  }
  __syncthreads();
  if (tid < K_) {
    int m = selm[tid];
    gkv[tid] = g[(size_t)b*M_ + m];
    float2 pv = pb2[m];
    bi0[tid] = x0 - pv.x;
    bi1[tid] = x1 - pv.y;
  }
  __syncthreads();

  // ---- Phase B: sin features: sfq fp32 [k][e], sfv fp16 in B-frag order ----
  if (tid < 64) {
    int e = tid & 31, cc = tid >> 5;
    float v = __sinf(cc ? bi1[e] : bi0[e]);
    sfq[cc*32 + e] = v;
    sfvB[fragpos(cc, e)] = (_Float16)v;
    sfq[(130 + cc)*32 + e] = 0.f;
  }
  for (int t = tid; t < 960; t += 256) {      // zero-pad frag k=130..159
    int k = 130 + (t >> 5), e = t & 31;
    sfvB[fragpos(k, e)] = (_Float16)0.f;
  }
  {
    const int e = tid & 31;
    const float s0 = PI_F*(bi0[e] + 1.f), s1 = PI_F*(bi1[e] + 1.f);
    for (int j = tid >> 5; j < 64; j += 8) {
      float eq = s0*w1q[j] + s1*w1q[64 + j];
      sfq[(2 + j)*32 + e]  = __sinf(eq);
      sfq[(66 + j)*32 + e] = __cosf(eq);
      float ev = s0*w1v[j] + s1*w1v[64 + j];
      sfvB[fragpos(2 + j, e)]  = (_Float16)__sinf(ev);
      sfvB[fragpos(66 + j, e)] = (_Float16)__cosf(ev);
    }
  }
  __syncthreads();

  // ---- Phase C: attention logits (waves 0,1), fp32 ----
  if (tid < 128) {
    const int e = tid >> 2, h = tid & 3;
    const int m = selm[e];
    const float* kwrow = kw + ((size_t)((b*M_ + m)*4 + h))*132;
    float accq = kb[(size_t)(b*M_ + m)*4 + h];
    const float4* kw4 = (const float4*)kwrow;
#pragma unroll 4
    for (int q4 = 0; q4 < 33; ++q4) {
      float4 kv = kw4[q4];
      int q = q4*4;
      accq = fmaf(sfq[q*32 + e],       kv.x, accq);
      accq = fmaf(sfq[(q + 1)*32 + e], kv.y, accq);
      accq = fmaf(sfq[(q + 2)*32 + e], kv.z, accq);
      accq = fmaf(sfq[(q + 3)*32 + e], kv.w, accq);
    }
    const float gk = gkv[e];
    logits_s[tid] = accq - seld[e]/(gk*gk);
  }

  // ---- GEMM1 (MFMA): C1T[256][32] = W2^T @ sfv^T ; wave owns mt = wid*4..+3 ----
  f32x4 acc1[4][2];
#pragma unroll
  for (int mi = 0; mi < 4; ++mi)
#pragma unroll
    for (int nt = 0; nt < 2; ++nt) acc1[mi][nt] = (f32x4)0.f;
  {
    const half8* w2f8  = (const half8*)w2f;
    const half8* sfvB8 = (const half8*)sfvB;
#pragma unroll
    for (int ks = 0; ks < 5; ++ks) {
      half8 bf0 = sfvB8[(0*5 + ks)*64 + lane];
      half8 bf1 = sfvB8[(1*5 + ks)*64 + lane];
#pragma unroll
      for (int mi = 0; mi < 4; ++mi) {
        half8 af = w2f8[((wid*4 + mi)*5 + ks)*64 + lane];
        acc1[mi][0] = __builtin_amdgcn_mfma_f32_16x16x32_f16(af, bf0, acc1[mi][0], 0, 0, 0);
        acc1[mi][1] = __builtin_amdgcn_mfma_f32_16x16x32_f16(af, bf1, acc1[mi][1], 0, 0, 0);
      }
    }
  }
  __syncthreads();   // everyone past C (sfq dead) and past GEMM1 (sfvB dead)

  // ---- epilogue: waves 0,1 -> evlds (fp16); waves 2,3 -> tpart (fp32) ----
  if (wid < 2) {
#pragma unroll
    for (int mi = 0; mi < 4; ++mi) {
      const int j0 = (wid*4 + mi)*16 + ((lane >> 4) << 2);
#pragma unroll
      for (int nt = 0; nt < 2; ++nt) {
        const int e = nt*16 + (lane & 15);
        const float4 v4 = *(const float4*)(vf + ((size_t)(b*M_ + selm[e]))*NH_ + j0);
        f32x4 a = acc1[mi][nt];
        half4v hv;
        hv[0] = (_Float16)(v4.x * a[0]);
        hv[1] = (_Float16)(v4.y * a[1]);
        hv[2] = (_Float16)(v4.z * a[2]);
        hv[3] = (_Float16)(v4.w * a[3]);
        *(half4v*)(evlds + e*136 + j0) = hv;
      }
    }
  } else {
#pragma unroll
    for (int mi = 0; mi < 4; ++mi) {
      const int j0 = ((wid - 2)*4 + mi)*16 + ((lane >> 4) << 2);
      const float4 c4 = *(const float4*)(cgv + j0);
#pragma unroll
      for (int nt = 0; nt < 2; ++nt) {
        const int e = nt*16 + (lane & 15);
        const float4 b4 = *(const float4*)(base + ((size_t)(b*M_ + selm[e]))*NH_ + j0);
        f32x4 a = acc1[mi][nt];
        float4 t;
        t.x = a[0] + b4.x + c4.x;
        t.y = a[1] + b4.y + c4.y;
        t.z = a[2] + b4.z + c4.z;
        t.w = a[3] + b4.w + c4.w;
        *(float4*)(tpart + e*132 + j0) = t;
      }
    }
  }
  __syncthreads();

  // ---- GEMM2 (MFMA): C2T[128][32] = wv1^T @ ev^T ; wave owns mt2 = 2w,2w+1 ----
  f32x4 acc2[2][2];
#pragma unroll
  for (int mi = 0; mi < 2; ++mi)
#pragma unroll
    for (int nt = 0; nt < 2; ++nt) acc2[mi][nt] = (f32x4)0.f;
  {
    const half8* wv1f8 = (const half8*)wv1f;
    const half8* evB   = (const half8*)evlds;   // index: e*17 + ks*4 + (lane>>4)
#pragma unroll
    for (int ks = 0; ks < 4; ++ks) {
      half8 bf0 = evB[(lane & 15)*17 + ks*4 + (lane >> 4)];
      half8 bf1 = evB[(16 + (lane & 15))*17 + ks*4 + (lane >> 4)];
#pragma unroll
      for (int mi = 0; mi < 2; ++mi) {
        half8 af = wv1f8[((2*wid + mi)*4 + ks)*64 + lane];
        acc2[mi][0] = __builtin_amdgcn_mfma_f32_16x16x32_f16(af, bf0, acc2[mi][0], 0, 0, 0);
        acc2[mi][1] = __builtin_amdgcn_mfma_f32_16x16x32_f16(af, bf1, acc2[mi][1], 0, 0, 0);
      }
    }
  }
  // gelu epilogue (per-owner in-place on tpart)
#pragma unroll
  for (int mi = 0; mi < 2; ++mi) {
    const int j0 = (2*wid + mi)*16 + ((lane >> 4) << 2);
#pragma unroll
    for (int nt = 0; nt < 2; ++nt) {
      const int e = nt*16 + (lane & 15);
      float4 tp = *(float4*)(tpart + e*132 + j0);
      f32x4 a = acc2[mi][nt];
      float tv[4] = {a[0] + tp.x, a[1] + tp.y, a[2] + tp.z, a[3] + tp.w};
      float4 gv;
      float* gvp = &gv.x;
#pragma unroll
      for (int jj = 0; jj < 4; ++jj) {
        float tval = tv[jj];
        float u = 0.79788456080286536f*(tval + 0.044715f*tval*tval*tval);
        float ex = __expf(2.f*u);
        float th = 1.f - 2.f/(ex + 1.f);
        gvp[jj] = 0.5f*tval*(1.f + th);
      }
      *(float4*)(tpart + e*132 + j0) = gv;
    }
  }
  __syncthreads();

  // ---- Phase F: po[e][12] = gt[e] @ wvoT^T (fp32) ----
  for (int t = tid; t < K_*12; t += 256) {
    const int e = t / 12, r = t - (t/12)*12;
    const float4* wr4 = (const float4*)(wvoT + r*NH_);
    const float4* gr4 = (const float4*)(tpart + e*132);
    float a0 = 0.f, a1 = 0.f, a2 = 0.f, a3 = 0.f;
#pragma unroll 4
    for (int q = 0; q < NH_/4; ++q) {
      float4 wq = wr4[q], gq = gr4[q];
      a0 = fmaf(gq.x, wq.x, a0);
      a1 = fmaf(gq.y, wq.y, a1);
      a2 = fmaf(gq.z, wq.z, a2);
      a3 = fmaf(gq.w, wq.w, a3);
    }
    poL[t] = (a0 + a1) + (a2 + a3);
  }
  __syncthreads();

  // ---- Phase G: softmax over K per head + combine ----
  if (tid < 128) {
    const int h = tid >> 5, e = tid & 31;
    float l = logits_s[e*4 + h];
    float mx = l;
#pragma unroll
    for (int off = 1; off < 32; off <<= 1) mx = fmaxf(mx, __shfl_xor(mx, off));
    float w = __expf(l - mx);
    float s = w;
#pragma unroll
    for (int off = 1; off < 32; off <<= 1) s += __shfl_xor(s, off);
    float att = w / s;
    float p0 = att * poL[e*12 + h*3 + 0];
    float p1 = att * poL[e*12 + h*3 + 1];
    float p2 = att * poL[e*12 + h*3 + 2];
#pragma unroll
    for (int off = 1; off < 32; off <<= 1) {
      p0 += __shfl_xor(p0, off);
      p1 += __shfl_xor(p1, off);
      p2 += __shfl_xor(p2, off);
    }
    if (e == 0) { hpart[h*4 + 0] = p0; hpart[h*4 + 1] = p1; hpart[h*4 + 2] = p2; }
  }
  __syncthreads();
  if (tid < 3) {
    out[(size_t)bn*3 + tid] = outconst[tid]
        + hpart[0*4 + tid] + hpart[1*4 + tid] + hpart[2*4 + tid] + hpart[3*4 + tid];
  }
}

extern "C" void kernel_launch(void* const* d_in, const int* in_sizes, int n_in,
                              void* d_out, int out_size, void* d_ws, size_t ws_size,
                              hipStream_t stream) {
  (void)in_sizes; (void)n_in; (void)out_size; (void)ws_size;
  const float* x    = (const float*)d_in[0];
  const float* p    = (const float*)d_in[1];
  const float* c    = (const float*)d_in[2];
  const float* g    = (const float*)d_in[3];
  const float* w1q  = (const float*)d_in[4];
  const float* w2q  = (const float*)d_in[5];
  const float* b2q  = (const float*)d_in[6];
  const float* w3q  = (const float*)d_in[7];
  const float* b3q  = (const float*)d_in[8];
  const float* w1v  = (const float*)d_in[9];
  const float* w2v  = (const float*)d_in[10];
  const float* b2v  = (const float*)d_in[11];
  const float* w3v  = (const float*)d_in[12];
  const float* b3v  = (const float*)d_in[13];
  const float* wk   = (const float*)d_in[14];
  const float* bk   = (const float*)d_in[15];
  const float* wvw  = (const float*)d_in[16];
  const float* bv   = (const float*)d_in[17];
  const float* wv1  = (const float*)d_in[18];
  const float* bv1  = (const float*)d_in[19];
  const float* wv2  = (const float*)d_in[20];
  const float* bv2  = (const float*)d_in[21];
  const float* wout = (const float*)d_in[22];
  const float* bout = (const float*)d_in[23];
  float* ws = (float*)d_ws;
  float* outp = (float*)d_out;

  hipLaunchKernelGGL(enf_wgw, dim3(64), dim3(256), 0, stream, w3v, wv1, ws + OFF_WGW);
  hipLaunchKernelGGL(enf_w2, dim3(130), dim3(256), 0, stream, w2v, w3v, ws + OFF_WGW, ws + OFF_W2);
  hipLaunchKernelGGL(enf_w2frag, dim3(160), dim3(256), 0, stream,
                     ws + OFF_W2, (_Float16*)(ws + OFF_W2F));
  hipLaunchKernelGGL(enf_wv1frag, dim3(64), dim3(256), 0, stream,
                     wv1, (_Float16*)(ws + OFF_WV1F));
  hipLaunchKernelGGL(enf_consts, dim3(1), dim3(256), 0, stream,
                     b2v, w3v, b3v, ws + OFF_WGW, wv1, bv1, wv2, wout, bv2, bout,
                     ws + OFF_CB, ws + OFF_CGV, ws + OFF_WVOT, ws + OFF_OUTC);
  hipLaunchKernelGGL(enf_latent, dim3(B_*M_), dim3(256), 0, stream,
                     c, wk, bk, wvw, bv, w3q, b3q, w2q, b2q, wv1, ws + OFF_CB,
                     ws + OFF_KW, ws + OFF_KB, ws + OFF_VF, ws + OFF_BASE);
  hipLaunchKernelGGL(enf_main, dim3(B_*N_), dim3(256), 0, stream,
                     x, p, g, w1q, w1v,
                     (const _Float16*)(ws + OFF_W2F), (const _Float16*)(ws + OFF_WV1F),
                     ws + OFF_CGV, ws + OFF_WVOT, ws + OFF_OUTC,
                     ws + OFF_KW, ws + OFF_KB, ws + OFF_VF, ws + OFF_BASE, outp);
}

// Round 4
// 398.495 us; speedup vs baseline: 3.2928x; 1.4026x over previous
//
#include <hip/hip_runtime.h>
#include <math.h>

#define B_ 4
#define N_ 2048
#define M_ 1024
#define K_ 32
#define HEADS_ 4
#define NH_ 128
#define PI_F 3.14159265358979323846f

typedef unsigned long long ull;
typedef __attribute__((ext_vector_type(8))) _Float16 half8;
typedef __attribute__((ext_vector_type(4))) _Float16 half4v;
typedef __attribute__((ext_vector_type(4))) float f32x4;

// workspace offsets (in floats)
#define OFF_WGW   0            // 128*128
#define OFF_W2    16384        // 130*256  [WB | WG]
#define OFF_CB    49664        // 128
#define OFF_CGV   49792        // 128
#define OFF_WVOT  49920        // 12*128
#define OFF_OUTC  51456        // 4
#define OFF_KW    51460        // B*M*4*132
#define OFF_KB    2214148      // B*M*4
#define OFF_VF    2230532      // B*M*128
#define OFF_BASE  2754820      // B*M*128
#define OFF_W2F   3279108      // 40960 halfs = 20480 floats (W2^T MFMA A-frags)
#define OFF_WV1F  3299588      // 16384 halfs = 8192 floats  (wv1^T MFMA A-frags)
#define OFF_U     3307780      // 130*256 = 33280 (U = w2q@w3v-style fold: w2q@w3q)
#define OFF_E     3341060      // 256
#define OFF_WQK   3341316      // 128*524 = 67072  [kw 520 | kb 4] per l row
#define OFF_KWCC  3408388      // 524 consts
// total = 3408912 floats (~13.6 MB)

// ---------- precompute stage A: WGW | U | E ----------
__global__ void enf_preA(const float* __restrict__ w3v, const float* __restrict__ wv1,
                         const float* __restrict__ w2q, const float* __restrict__ w3q,
                         const float* __restrict__ b2q, const float* __restrict__ b3q,
                         float* __restrict__ WGW, float* __restrict__ U,
                         float* __restrict__ E) {
  const int blk = blockIdx.x, tid = threadIdx.x;
  if (blk < 64) {            // WGW[i][j] = sum_r w3v[i][128+r]*wv1[r][j]
    int o = blk*256 + tid;
    int i = o >> 7, j = o & 127;
    float acc = 0.f;
    for (int r = 0; r < 128; ++r) acc = fmaf(w3v[i*256 + 128 + r], wv1[r*128 + j], acc);
    WGW[o] = acc;
  } else if (blk < 194) {    // U[a][s] = sum_i w2q[a][i]*w3q[i][s]
    int a = blk - 64, s = tid;
    float acc = 0.f;
    for (int i = 0; i < 128; ++i) acc = fmaf(w2q[a*128 + i], w3q[i*256 + s], acc);
    U[a*256 + s] = acc;
  } else {                   // E[s] = sum_j b2q[j]*w3q[j][s] + b3q[s]
    int s = tid;
    float acc = b3q[s];
    for (int j = 0; j < 128; ++j) acc = fmaf(b2q[j], w3q[j*256 + s], acc);
    E[s] = acc;
  }
}

// ---------- precompute stage B: W2 | consts | WQK | kwcc ----------
__global__ void enf_preB(const float* __restrict__ w2v, const float* __restrict__ w3v,
                         const float* __restrict__ WGW, const float* __restrict__ U,
                         const float* __restrict__ E, const float* __restrict__ wk,
                         const float* __restrict__ bk,
                         const float* __restrict__ b2v, const float* __restrict__ b3v,
                         const float* __restrict__ wv1, const float* __restrict__ bv1,
                         const float* __restrict__ wv2, const float* __restrict__ wout,
                         const float* __restrict__ bv2, const float* __restrict__ bout,
                         float* __restrict__ W2, float* __restrict__ cb,
                         float* __restrict__ cgv, float* __restrict__ wvoT,
                         float* __restrict__ outconst, float* __restrict__ WQK,
                         float* __restrict__ kwcc) {
  const int blk = blockIdx.x, t = threadIdx.x;
  if (blk < 130) {           // W2
    int a = blk, j = t;
    float acc = 0.f;
    if (j < 128) {
      for (int i = 0; i < 128; ++i) acc = fmaf(w2v[a*128 + i], w3v[i*256 + j], acc);
    } else {
      int j2 = j - 128;
      for (int i = 0; i < 128; ++i) acc = fmaf(w2v[a*128 + i], WGW[i*128 + j2], acc);
    }
    W2[a*256 + j] = acc;
  } else if (blk == 130) {   // consts
    if (t < 128) {
      float a1 = 0.f;
      for (int i = 0; i < 128; ++i) a1 = fmaf(b2v[i], w3v[i*256 + t], a1);
      cb[t] = a1 + b3v[t];
      float a2 = 0.f;
      for (int i = 0; i < 128; ++i) a2 = fmaf(b2v[i], WGW[i*128 + t], a2);
      for (int r = 0; r < 128; ++r) a2 = fmaf(b3v[128 + r], wv1[r*128 + t], a2);
      cgv[t] = a2 + bv1[t];
    }
    for (int o = t; o < 1536; o += 256) {
      int r12 = o >> 7, i = o & 127;
      int h = r12 / 3, c = r12 - h*3;
      float acc = 0.f;
      for (int k = 0; k < 128; ++k)
        acc = fmaf(wv2[i*512 + h*128 + k], wout[(h*128 + k)*3 + c], acc);
      wvoT[r12*128 + i] = acc;
    }
    if (t < 3) {
      float acc = bout[t];
      for (int r = 0; r < 512; ++r) acc = fmaf(bv2[r], wout[r*3 + t], acc);
      outconst[t] = acc;
    }
  } else if (blk < 259) {    // WQK row l: [kw 520 | kb 4]
    int l = blk - 131;
    for (int col = t; col < 524; col += 256) {
      float acc = 0.f;
      if (col < 520) {
        int h = col / 130, a = col - h*130;
        const float* ur = U + a*256 + h*64;
        const float* wr = wk + l*256 + h*64;
        for (int q = 0; q < 64; ++q) acc = fmaf(ur[q], wr[q], acc);
      } else {
        int h = col - 520;
        const float* er = E + h*64;
        const float* wr = wk + l*256 + h*64;
        for (int q = 0; q < 64; ++q) acc = fmaf(er[q], wr[q], acc);
      }
      WQK[l*524 + col] = acc;
    }
  } else {                   // kwcc consts
    for (int col = t; col < 524; col += 256) {
      float acc = 0.f;
      if (col < 520) {
        int h = col / 130, a = col - h*130;
        const float* ur = U + a*256 + h*64;
        const float* br = bk + h*64;
        for (int q = 0; q < 64; ++q) acc = fmaf(ur[q], br[q], acc);
      } else {
        int h = col - 520;
        const float* er = E + h*64;
        const float* br = bk + h*64;
        for (int q = 0; q < 64; ++q) acc = fmaf(er[q], br[q], acc);
      }
      kwcc[col] = acc;
    }
  }
}

// ---------- precompute stage C: MFMA A-fragments ----------
__global__ void enf_preC(const float* __restrict__ W2, const float* __restrict__ wv1,
                         _Float16* __restrict__ W2f, _Float16* __restrict__ wv1f) {
  const int blk = blockIdx.x, tid = threadIdx.x;
  if (blk < 160) {           // W2^T frags: [mt16][ks5][lane64][i8]
    int idx = blk*256 + tid;
    int i = idx & 7, lane = (idx >> 3) & 63;
    int rest = idx >> 9;
    int ks = rest % 5, mt = rest / 5;
    int k = ks*32 + ((lane >> 4) << 3) + i;
    int n = mt*16 + (lane & 15);
    W2f[idx] = (k < 130) ? (_Float16)W2[k*256 + n] : (_Float16)0.f;
  } else {                   // wv1^T frags: [mt8][ks4][lane64][i8]
    int idx = (blk - 160)*256 + tid;
    int i = idx & 7, lane = (idx >> 3) & 63;
    int rest = idx >> 9;
    int ks = rest & 3, mt = rest >> 2;
    int k = ks*32 + ((lane >> 4) << 3) + i;
    int j = mt*16 + (lane & 15);
    wv1f[idx] = (_Float16)wv1[k*128 + j];
  }
}

// ---------- latent kernel: 4 latents per block ----------
__global__ __launch_bounds__(256) void enf_latent(
    const float* __restrict__ c, const float* __restrict__ wvw,
    const float* __restrict__ bv, const float* __restrict__ WQK,
    const float* __restrict__ kwcc, const float* __restrict__ cb,
    const float* __restrict__ wv1,
    float* __restrict__ kw, float* __restrict__ kb,
    float* __restrict__ vf_o, float* __restrict__ base_o) {
  const int bm0 = blockIdx.x * 4;
  const int tid = threadIdx.x;
  __shared__ float cls[4][128];
  __shared__ float evs[4][128];
  for (int t = tid; t < 512; t += 256) cls[t >> 7][t & 127] = c[(size_t)bm0*128 + t];
  __syncthreads();
  for (int col = tid; col < 652; col += 256) {
    float a0 = 0.f, a1 = 0.f, a2 = 0.f, a3 = 0.f;
    if (col < 128) {
      for (int l = 0; l < 128; ++l) {
        float w = wvw[l*128 + col];
        a0 = fmaf(cls[0][l], w, a0);
        a1 = fmaf(cls[1][l], w, a1);
        a2 = fmaf(cls[2][l], w, a2);
        a3 = fmaf(cls[3][l], w, a3);
      }
      float bvc = bv[col];
      a0 += bvc; a1 += bvc; a2 += bvc; a3 += bvc;
      vf_o[(size_t)(bm0 + 0)*128 + col] = a0;
      vf_o[(size_t)(bm0 + 1)*128 + col] = a1;
      vf_o[(size_t)(bm0 + 2)*128 + col] = a2;
      vf_o[(size_t)(bm0 + 3)*128 + col] = a3;
      float cbf = 1.f + cb[col];
      evs[0][col] = a0*cbf; evs[1][col] = a1*cbf;
      evs[2][col] = a2*cbf; evs[3][col] = a3*cbf;
    } else {
      const float* wq = WQK + (col - 128);
      for (int l = 0; l < 128; ++l) {
        float w = wq[l*524];
        a0 = fmaf(cls[0][l], w, a0);
        a1 = fmaf(cls[1][l], w, a1);
        a2 = fmaf(cls[2][l], w, a2);
        a3 = fmaf(cls[3][l], w, a3);
      }
      float cc = kwcc[col - 128];
      a0 += cc; a1 += cc; a2 += cc; a3 += cc;
      if (col < 648) {
        int h = (col - 128) / 130, a = (col - 128) - h*130;
        kw[((size_t)(bm0 + 0)*4 + h)*132 + a] = a0;
        kw[((size_t)(bm0 + 1)*4 + h)*132 + a] = a1;
        kw[((size_t)(bm0 + 2)*4 + h)*132 + a] = a2;
        kw[((size_t)(bm0 + 3)*4 + h)*132 + a] = a3;
      } else {
        int h = col - 648;
        kb[(size_t)(bm0 + 0)*4 + h] = a0;
        kb[(size_t)(bm0 + 1)*4 + h] = a1;
        kb[(size_t)(bm0 + 2)*4 + h] = a2;
        kb[(size_t)(bm0 + 3)*4 + h] = a3;
      }
    }
  }
  if (tid < 32)   // zero pad kw cols 130,131
    kw[((size_t)(bm0 + (tid >> 3))*4 + ((tid >> 1) & 3))*132 + 130 + (tid & 1)] = 0.f;
  __syncthreads();
  for (int t = tid; t < 512; t += 256) {
    int i = t >> 7, j = t & 127;
    float acc = 0.f;
    for (int l = 0; l < 128; ++l) acc = fmaf(evs[i][l], wv1[l*128 + j], acc);
    base_o[(size_t)(bm0 + i)*128 + j] = acc;
  }
}

// sfv B-fragment position: [nt(2)][ks(5)][lane(64)][i(8)] halfs
__device__ __forceinline__ int fragpos(int k, int e) {
  return ((((e >> 4)*5 + (k >> 5))*64 + (((k >> 3) & 3) << 4) + (e & 15)) << 3) + (k & 7);
}

// ---------- main kernel: one block per (b,n) ----------
__global__ __launch_bounds__(256, 5) void enf_main(
    const float* __restrict__ x, const float* __restrict__ p,
    const float* __restrict__ g,
    const float* __restrict__ w1q, const float* __restrict__ w1v,
    const _Float16* __restrict__ w2f, const _Float16* __restrict__ wv1f,
    const float* __restrict__ cgv, const float* __restrict__ wvoT,
    const float* __restrict__ outconst,
    const float* __restrict__ kw, const float* __restrict__ kb,
    const float* __restrict__ vf, const float* __restrict__ base,
    float* __restrict__ out) {
  const int bn = blockIdx.x;
  const int b = bn >> 11;          // N = 2048
  const int tid = threadIdx.x;
  const int lane = tid & 63;
  const int wid = tid >> 6;

  // S timeline: [0..4224) sfq fp32 [132][32]  ->  [0..2176) evlds half[32][136], then poL[384]
  //             [4224..6784) sfvB (5120 halfs) ;  [2560..6784) gt fp32 [32][132]
  __shared__ alignas(16) float S[6784];
  __shared__ int   selm[K_];
  __shared__ float seld[K_];
  __shared__ float gkv[K_];
  __shared__ float bi0[K_], bi1[K_];
  __shared__ float logits_s[K_*HEADS_];
  __shared__ float hpart[HEADS_*4];

  float* candd = S;
  int*   candm = (int*)(S + 128);
  float* sfq   = S;                         // [132][32]
  _Float16* sfvB = (_Float16*)(S + 4224);   // 5120 halfs
  _Float16* evlds = (_Float16*)S;           // [32][136]
  float* gt    = S + 2560;                  // [32][132]
  float* poL   = S;                         // [32][12]

  const float x0 = x[bn*2 + 0];
  const float x1 = x[bn*2 + 1];
  const float2* pb2 = (const float2*)(p + (size_t)b*M_*2);

  // ---- Phase A: per-wave top-32 via binary-search threshold on float bits ----
  unsigned db[4]; int mm[4];
#pragma unroll
  for (int s = 0; s < 4; ++s) {
    int m = wid*256 + s*64 + lane;
    float2 pv = pb2[m];
    float d0 = x0 - pv.x, d1 = x1 - pv.y;
    float d = __fadd_rn(__fmul_rn(d0, d0), __fmul_rn(d1, d1));
    db[s] = __float_as_uint(d);
    mm[s] = m;
  }
  unsigned xth = 0;
  for (int bit = 30; bit >= 0; --bit) {
    unsigned trial = xth | (1u << bit);
    int cnt = __popcll(__ballot(db[0] < trial)) + __popcll(__ballot(db[1] < trial))
            + __popcll(__ballot(db[2] < trial)) + __popcll(__ballot(db[3] < trial));
    if (cnt < 32) xth = trial;
  }
  // xth = bits of the 32nd-smallest distance in this wave
  {
    ull bl[4], be[4];
#pragma unroll
    for (int s = 0; s < 4; ++s) {
      bl[s] = __ballot(db[s] < xth);
      be[s] = __ballot(db[s] == xth);
    }
    int r = __popcll(bl[0]) + __popcll(bl[1]) + __popcll(bl[2]) + __popcll(bl[3]);
    const ull lmask = (1ull << lane) - 1ull;
    int pl = 0, pe = 0;
#pragma unroll
    for (int s = 0; s < 4; ++s) {
      if (db[s] < xth) {
        int pos = pl + __popcll(bl[s] & lmask);
        candd[wid*K_ + pos] = __uint_as_float(db[s]);
        candm[wid*K_ + pos] = mm[s];
      } else if (db[s] == xth) {
        int pos = r + pe + __popcll(be[s] & lmask);
        if (pos < K_) {
          candd[wid*K_ + pos] = __uint_as_float(db[s]);
          candm[wid*K_ + pos] = mm[s];
        }
      }
      pl += __popcll(bl[s]);
      pe += __popcll(be[s]);
    }
  }
  __syncthreads();
  // merge 128 candidates -> exact global top-32 (rank; ties by candidate idx)
  if (tid < 128) {
    float d = candd[tid];
    int m = candm[tid];
    int rank = 0;
    for (int i = 0; i < 128; ++i) {
      float di = candd[i];
      rank += (di < d || (di == d && i < tid)) ? 1 : 0;
    }
    if (rank < K_) { selm[rank] = m; seld[rank] = d; }
  }
  __syncthreads();
  if (tid < K_) {
    int m = selm[tid];
    gkv[tid] = g[(size_t)b*M_ + m];
    float2 pv = pb2[m];
    bi0[tid] = x0 - pv.x;
    bi1[tid] = x1 - pv.y;
  }
  __syncthreads();

  // ---- Phase B: sin features: sfq fp32 [k][e], sfv fp16 in B-frag order ----
  if (tid < 64) {
    int e = tid & 31, cc = tid >> 5;
    float v = __sinf(cc ? bi1[e] : bi0[e]);
    sfq[cc*32 + e] = v;
    sfvB[fragpos(cc, e)] = (_Float16)v;
    sfq[(130 + cc)*32 + e] = 0.f;
  }
  for (int t = tid; t < 960; t += 256) {      // zero-pad frag k=130..159
    int k = 130 + (t >> 5), e = t & 31;
    sfvB[fragpos(k, e)] = (_Float16)0.f;
  }
  {
    const int e = tid & 31;
    const float s0 = PI_F*(bi0[e] + 1.f), s1 = PI_F*(bi1[e] + 1.f);
    for (int j = tid >> 5; j < 64; j += 8) {
      float eq = s0*w1q[j] + s1*w1q[64 + j];
      sfq[(2 + j)*32 + e]  = __sinf(eq);
      sfq[(66 + j)*32 + e] = __cosf(eq);
      float ev = s0*w1v[j] + s1*w1v[64 + j];
      sfvB[fragpos(2 + j, e)]  = (_Float16)__sinf(ev);
      sfvB[fragpos(66 + j, e)] = (_Float16)__cosf(ev);
    }
  }
  __syncthreads();

  // ---- Phase C: attention logits (waves 0,1), fp32; waves 2,3 go to GEMM1 ----
  if (tid < 128) {
    const int e = tid >> 2, h = tid & 3;
    const int m = selm[e];
    const float* kwrow = kw + ((size_t)((b*M_ + m)*4 + h))*132;
    float accq = kb[(size_t)(b*M_ + m)*4 + h];
    const float4* kw4 = (const float4*)kwrow;
#pragma unroll 4
    for (int q4 = 0; q4 < 33; ++q4) {
      float4 kv = kw4[q4];
      int q = q4*4;
      accq = fmaf(sfq[q*32 + e],       kv.x, accq);
      accq = fmaf(sfq[(q + 1)*32 + e], kv.y, accq);
      accq = fmaf(sfq[(q + 2)*32 + e], kv.z, accq);
      accq = fmaf(sfq[(q + 3)*32 + e], kv.w, accq);
    }
    const float gk = gkv[e];
    logits_s[tid] = accq - seld[e]/(gk*gk);
  }

  // ---- GEMM1 (MFMA): C1T = W2^T @ sfv^T
  // wave w owns mt in {2w, 2w+1} (evec cols) and {8+2w, 9+2w} (its own gterm cols)
  f32x4 acc1[4][2];
#pragma unroll
  for (int mi = 0; mi < 4; ++mi)
#pragma unroll
    for (int nt = 0; nt < 2; ++nt) acc1[mi][nt] = (f32x4)0.f;
  {
    const half8* w2f8  = (const half8*)w2f;
    const half8* sfvB8 = (const half8*)sfvB;
#pragma unroll
    for (int ks = 0; ks < 5; ++ks) {
      half8 bf0 = sfvB8[(0*5 + ks)*64 + lane];
      half8 bf1 = sfvB8[(1*5 + ks)*64 + lane];
#pragma unroll
      for (int mi = 0; mi < 4; ++mi) {
        const int mt = (mi < 2) ? (2*wid + mi) : (8 + 2*wid + (mi - 2));
        half8 af = w2f8[(mt*5 + ks)*64 + lane];
        acc1[mi][0] = __builtin_amdgcn_mfma_f32_16x16x32_f16(af, bf0, acc1[mi][0], 0, 0, 0);
        acc1[mi][1] = __builtin_amdgcn_mfma_f32_16x16x32_f16(af, bf1, acc1[mi][1], 0, 0, 0);
      }
    }
  }
  __syncthreads();   // all waves past C (sfq dead) and GEMM1 (sfvB dead)

  // ---- epilogue: evec (mi 0,1) -> evlds fp16; gterm (mi 2,3) -> registers ----
  f32x4 tg[2][2];
#pragma unroll
  for (int mi = 0; mi < 2; ++mi) {
    const int j0 = (2*wid + mi)*16 + ((lane >> 4) << 2);
#pragma unroll
    for (int nt = 0; nt < 2; ++nt) {
      const int e = nt*16 + (lane & 15);
      const float4 v4 = *(const float4*)(vf + ((size_t)(b*M_ + selm[e]))*NH_ + j0);
      f32x4 a = acc1[mi][nt];
      half4v hv;
      hv[0] = (_Float16)(v4.x * a[0]);
      hv[1] = (_Float16)(v4.y * a[1]);
      hv[2] = (_Float16)(v4.z * a[2]);
      hv[3] = (_Float16)(v4.w * a[3]);
      *(half4v*)(evlds + e*136 + j0) = hv;
    }
  }
#pragma unroll
  for (int mi = 0; mi < 2; ++mi) {
    const int j0 = 32*wid + mi*16 + ((lane >> 4) << 2);   // output col (gterm n-128)
    const float4 c4 = *(const float4*)(cgv + j0);
#pragma unroll
    for (int nt = 0; nt < 2; ++nt) {
      const int e = nt*16 + (lane & 15);
      const float4 b4 = *(const float4*)(base + ((size_t)(b*M_ + selm[e]))*NH_ + j0);
      f32x4 a = acc1[2 + mi][nt];
      tg[mi][nt][0] = a[0] + b4.x + c4.x;
      tg[mi][nt][1] = a[1] + b4.y + c4.y;
      tg[mi][nt][2] = a[2] + b4.z + c4.z;
      tg[mi][nt][3] = a[3] + b4.w + c4.w;
    }
  }
  __syncthreads();

  // ---- GEMM2 (MFMA): acc2 = tg + wv1^T @ ev^T ; wave owns mt2 = 2w, 2w+1 ----
  {
    const half8* wv1f8 = (const half8*)wv1f;
    const half8* evB   = (const half8*)evlds;   // index: e*17 + ks*4 + (lane>>4)
#pragma unroll
    for (int ks = 0; ks < 4; ++ks) {
      half8 bf0 = evB[(lane & 15)*17 + ks*4 + (lane >> 4)];
      half8 bf1 = evB[(16 + (lane & 15))*17 + ks*4 + (lane >> 4)];
#pragma unroll
      for (int mi = 0; mi < 2; ++mi) {
        half8 af = wv1f8[((2*wid + mi)*4 + ks)*64 + lane];
        tg[mi][0] = __builtin_amdgcn_mfma_f32_16x16x32_f16(af, bf0, tg[mi][0], 0, 0, 0);
        tg[mi][1] = __builtin_amdgcn_mfma_f32_16x16x32_f16(af, bf1, tg[mi][1], 0, 0, 0);
      }
    }
  }
  // gelu epilogue -> gt (disjoint from evlds; no barrier needed before write)
#pragma unroll
  for (int mi = 0; mi < 2; ++mi) {
    const int j0 = (2*wid + mi)*16 + ((lane >> 4) << 2);
#pragma unroll
    for (int nt = 0; nt < 2; ++nt) {
      const int e = nt*16 + (lane & 15);
      f32x4 a = tg[mi][nt];
      float4 gv;
      float* gvp = &gv.x;
#pragma unroll
      for (int jj = 0; jj < 4; ++jj) {
        float tval = a[jj];
        float u = 0.79788456080286536f*(tval + 0.044715f*tval*tval*tval);
        float ex = __expf(2.f*u);
        float th = 1.f - 2.f/(ex + 1.f);
        gvp[jj] = 0.5f*tval*(1.f + th);
      }
      *(float4*)(gt + e*132 + j0) = gv;
    }
  }
  __syncthreads();

  // ---- Phase F: po[e][12] = gt[e] @ wvoT^T (fp32) ----
  for (int t = tid; t < K_*12; t += 256) {
    const int e = t / 12, r = t - (t/12)*12;
    const float4* wr4 = (const float4*)(wvoT + r*NH_);
    const float4* gr4 = (const float4*)(gt + e*132);
    float a0 = 0.f, a1 = 0.f, a2 = 0.f, a3 = 0.f;
#pragma unroll 4
    for (int q = 0; q < NH_/4; ++q) {
      float4 wq = wr4[q], gq = gr4[q];
      a0 = fmaf(gq.x, wq.x, a0);
      a1 = fmaf(gq.y, wq.y, a1);
      a2 = fmaf(gq.z, wq.z, a2);
      a3 = fmaf(gq.w, wq.w, a3);
    }
    poL[t] = (a0 + a1) + (a2 + a3);
  }
  __syncthreads();

  // ---- Phase G: softmax over K per head + combine ----
  if (tid < 128) {
    const int h = tid >> 5, e = tid & 31;
    float l = logits_s[e*4 + h];
    float mx = l;
#pragma unroll
    for (int off = 1; off < 32; off <<= 1) mx = fmaxf(mx, __shfl_xor(mx, off));
    float w = __expf(l - mx);
    float s = w;
#pragma unroll
    for (int off = 1; off < 32; off <<= 1) s += __shfl_xor(s, off);
    float att = w / s;
    float p0 = att * poL[e*12 + h*3 + 0];
    float p1 = att * poL[e*12 + h*3 + 1];
    float p2 = att * poL[e*12 + h*3 + 2];
#pragma unroll
    for (int off = 1; off < 32; off <<= 1) {
      p0 += __shfl_xor(p0, off);
      p1 += __shfl_xor(p1, off);
      p2 += __shfl_xor(p2, off);
    }
    if (e == 0) { hpart[h*4 + 0] = p0; hpart[h*4 + 1] = p1; hpart[h*4 + 2] = p2; }
  }
  __syncthreads();
  if (tid < 3) {
    out[(size_t)bn*3 + tid] = outconst[tid]
        + hpart[0*4 + tid] + hpart[1*4 + tid] + hpart[2*4 + tid] + hpart[3*4 + tid];
  }
}

extern "C" void kernel_launch(void* const* d_in, const int* in_sizes, int n_in,
                              void* d_out, int out_size, void* d_ws, size_t ws_size,
                              hipStream_t stream) {
  (void)in_sizes; (void)n_in; (void)out_size; (void)ws_size;
  const float* x    = (const float*)d_in[0];
  const float* p    = (const float*)d_in[1];
  const float* c    = (const float*)d_in[2];
  const float* g    = (const float*)d_in[3];
  const float* w1q  = (const float*)d_in[4];
  const float* w2q  = (const float*)d_in[5];
  const float* b2q  = (const float*)d_in[6];
  const float* w3q  = (const float*)d_in[7];
  const float* b3q  = (const float*)d_in[8];
  const float* w1v  = (const float*)d_in[9];
  const float* w2v  = (const float*)d_in[10];
  const float* b2v  = (const float*)d_in[11];
  const float* w3v  = (const float*)d_in[12];
  const float* b3v  = (const float*)d_in[13];
  const float* wk   = (const float*)d_in[14];
  const float* bk   = (const float*)d_in[15];
  const float* wvw  = (const float*)d_in[16];
  const float* bv   = (const float*)d_in[17];
  const float* wv1  = (const float*)d_in[18];
  const float* bv1  = (const float*)d_in[19];
  const float* wv2  = (const float*)d_in[20];
  const float* bv2  = (const float*)d_in[21];
  const float* wout = (const float*)d_in[22];
  const float* bout = (const float*)d_in[23];
  float* ws = (float*)d_ws;
  float* outp = (float*)d_out;

  hipLaunchKernelGGL(enf_preA, dim3(195), dim3(256), 0, stream,
                     w3v, wv1, w2q, w3q, b2q, b3q,
                     ws + OFF_WGW, ws + OFF_U, ws + OFF_E);
  hipLaunchKernelGGL(enf_preB, dim3(260), dim3(256), 0, stream,
                     w2v, w3v, ws + OFF_WGW, ws + OFF_U, ws + OFF_E, wk, bk,
                     b2v, b3v, wv1, bv1, wv2, wout, bv2, bout,
                     ws + OFF_W2, ws + OFF_CB, ws + OFF_CGV, ws + OFF_WVOT,
                     ws + OFF_OUTC, ws + OFF_WQK, ws + OFF_KWCC);
  hipLaunchKernelGGL(enf_preC, dim3(224), dim3(256), 0, stream,
                     ws + OFF_W2, wv1,
                     (_Float16*)(ws + OFF_W2F), (_Float16*)(ws + OFF_WV1F));
  hipLaunchKernelGGL(enf_latent, dim3(B_*M_/4), dim3(256), 0, stream,
                     c, wvw, bv, ws + OFF_WQK, ws + OFF_KWCC, ws + OFF_CB, wv1,
                     ws + OFF_KW, ws + OFF_KB, ws + OFF_VF, ws + OFF_BASE);
  hipLaunchKernelGGL(enf_main, dim3(B_*N_), dim3(256), 0, stream,
                     x, p, g, w1q, w1v,
                     (const _Float16*)(ws + OFF_W2F), (const _Float16*)(ws + OFF_WV1F),
                     ws + OFF_CGV, ws + OFF_WVOT, ws + OFF_OUTC,
                     ws + OFF_KW, ws + OFF_KB, ws + OFF_VF, ws + OFF_BASE, outp);
}